// Round 7
// baseline (1144.290 us; speedup 1.0000x reference)
//
#include <hip/hip_runtime.h>
#include <hip/hip_bf16.h>
#include <hip/hip_fp16.h>
#include <stdint.h>

// GroupLinear: out[l,o] = sum_{g,i,j} x1[l,g*64+i]*x2[l,g*64+j]*W[o,(g*64+i)*64+j] + b[o]
// Round 14: occupancy 2 -> 3 blocks/CU. r13 math (per-SIMD units, rule #15):
// 2 waves/SIMD x 32 MFMA x 19.4 cyc = 1242 cyc matrix work vs 2360 cyc/iter = 53%
// = measured MfmaUtil; floor 132us. The 47% gap is VALU+issue slack that can't
// overlap with only 2 resident waves. VGPR 100+64acc=164 -> 3 waves/SIMD fit.
// SPLITK 4 -> 8 (KITERS=128, g-aligned, all boundary logic untouched), grid 1024:
// 768 resident + 256 backfill. launch_bounds(256,3) pins the allocator.
// Datapath unchanged from r13 (fp16 frags direct from Wt, pk_mul A-build).

#define L_DIM 2048
#define H_DIM 1024
#define O_DIM 1024
#define KDIM  65536

constexpr int BM = 128, BN = 128;
constexpr int SPLITK = 8;
constexpr int KITERS = 1024 / SPLITK;   // 128 (g,i) pairs per block (2 groups of 64)

typedef __attribute__((ext_vector_type(8))) _Float16 f16x8;
typedef __attribute__((ext_vector_type(8))) short bf16x8;
typedef __attribute__((ext_vector_type(8))) unsigned short u16x8;
typedef __attribute__((ext_vector_type(4))) float f32x4;
typedef __attribute__((ext_vector_type(4))) unsigned int u32x4;

__device__ __forceinline__ unsigned short f2b(float x) {
    __hip_bfloat16 h = __float2bfloat16(x);
    unsigned short u;
    __builtin_memcpy(&u, &h, 2);
    return u;
}

__device__ __forceinline__ unsigned hpk2(float a, float b) {   // two f32 -> packed half2
    __half2 h = __floats2half2_rn(a, b);
    unsigned u;
    __builtin_memcpy(&u, &h, 4);
    return u;
}

__device__ __forceinline__ unsigned h2u(__half2 h) {           // half2 bits -> unsigned
    unsigned u;
    __builtin_memcpy(&u, &h, 4);
    return u;
}

// ---- fused: out[l][o] = bias[o]  AND  W fp32 -> Wt fp16 fragment-order swizzle ----
// Grid must be exactly 2048 x 256 (init covers 2M floats, 1 f32x4/thread).
__global__ __launch_bounds__(256) void w_cvt(const float* __restrict__ W,
                                             unsigned short* __restrict__ Wt,
                                             const float* __restrict__ bias,
                                             float* __restrict__ out) {
    const int idx = blockIdx.x * 256 + threadIdx.x;
    {   // bias init (atomic-accumulation base)
        const int o = (idx * 4) & (O_DIM - 1);
        f32x4 bv = *reinterpret_cast<const f32x4*>(bias + o);
        reinterpret_cast<f32x4*>(out)[idx] = bv;
    }
    // fragment swizzle: Wt[((kc*64 + nt)*64 + lane)*8 + e] =
    //   fp16(W[nt*16 + (lane&15)][kc*32 + (lane>>4)*8 + e])
    const int lane = threadIdx.x & 63;
    const int l16  = lane & 15;
    const int quad = lane >> 4;
    const int wv   = blockIdx.x * 4 + (threadIdx.x >> 6);
    #pragma unroll
    for (int s = 0; s < 16; ++s) {
        const int u  = wv * 16 + s;
        const int kc = u >> 6;          // 32-col K-chunk
        const int nt = u & 63;          // 16-row N-tile
        const float* src = W + (size_t)(nt * 16 + l16) * KDIM + kc * 32 + quad * 8;
        f32x4 a = *reinterpret_cast<const f32x4*>(src);
        f32x4 b = *reinterpret_cast<const f32x4*>(src + 4);
        u32x4 pk;
        pk[0] = hpk2(a.x, a.y); pk[1] = hpk2(a.z, a.w);
        pk[2] = hpk2(b.x, b.y); pk[3] = hpk2(b.z, b.w);
        *reinterpret_cast<u16x8*>(Wt + (size_t)u * 512 + lane * 8) =
            __builtin_bit_cast(u16x8, pk);
    }
}

// ---- standalone init (fallback path only) ----
__global__ __launch_bounds__(256) void gl_init(const float* __restrict__ bias,
                                               float* __restrict__ out) {
    int idx = blockIdx.x * 256 + threadIdx.x;
    int o = (idx * 4) & (O_DIM - 1);
    f32x4 bv = *reinterpret_cast<const f32x4*>(bias + o);
    reinterpret_cast<f32x4*>(out)[idx] = bv;
}

// ---- main GEMM: fp16 frags direct from Wt; pk_mul A-build; no W LDS/barriers ----
__global__ __launch_bounds__(256, 3) void gl_gemm(const float* __restrict__ x1,
                                                  const float* __restrict__ x2,
                                                  const unsigned short* __restrict__ Wt,
                                                  float* __restrict__ out) {
    __shared__ unsigned X1s[64 * 128];            // 32 KB, [col][row], dup'd half2

    const int tid  = threadIdx.x;
    const int lane = tid & 63;
    const int wid  = tid >> 6;
    const int wm   = (wid >> 1) * 64;
    const int wn   = (wid & 1) * 64;
    const int quad = lane >> 4;
    const int l16  = lane & 15;

    // n in low 3 bits -> blocks sharing one W n-slab co-locate per XCD (L2 reuse)
    const int id  = blockIdx.x;
    const int n0  = (id & 7) * BN;
    const int m0  = ((id >> 3) & 15) * BM;
    const int kk0 = (id >> 7) * KITERS;     // (g,i)-pair index base, multiple of 64

    unsigned aoff[4];                       // x1/x2 row offsets (floats)
    #pragma unroll
    for (int t = 0; t < 4; ++t)
        aoff[t] = (unsigned)(m0 + wm + t * 16 + l16) * H_DIM;
    const unsigned qo = quad * 8;

    // per-thread B-frag base: Wt element ((kc*64 + ntile)*64 + lane)*8
    const unsigned short* gWt = Wt + (size_t)kk0 * 65536
                                   + (size_t)((n0 + wn) >> 4) * 512 + lane * 8;

    f32x4 acc[4][4] = {};
    __half2 x2h[4][8];      // per-g x2 slice: [mt][ks*4 + pair], pairs of j at ks*32+qo
    f16x8 fE[8], fO[8];     // NAMED frag sets, depth-1 prefetch (rule #20)
    __half2 xc[4], xn[4];   // x1 current / next (duplicated halves)

    auto loadF = [&](int t, f16x8 (&f)[8]) {
        const unsigned short* p = gWt + (size_t)t * 65536;
        #pragma unroll
        for (int ks = 0; ks < 2; ++ks)
            #pragma unroll
            for (int nt = 0; nt < 4; ++nt)
                f[ks * 4 + nt] = *reinterpret_cast<const f16x8*>(
                    p + ks * 32768 + nt * 512);
    };
    auto loadXC = [&](int t, __half2 (&v)[4]) {
        const unsigned* xp = &X1s[(t & 63) * 128 + wm + l16];
        unsigned a = xp[0], b = xp[16], c = xp[32], d = xp[48];
        __builtin_memcpy(&v[0], &a, 4); __builtin_memcpy(&v[1], &b, 4);
        __builtin_memcpy(&v[2], &c, 4); __builtin_memcpy(&v[3], &d, 4);
    };
    auto stageX1 = [&](int t) {             // stage x1 g-slab -> X1s[col][row] dup'd half2
        const int r0 = tid >> 1;
        const int cb = (tid & 1) * 32;
        const float* xr = x1 + (size_t)(m0 + r0) * H_DIM + (unsigned)(kk0 + t) + cb;
        #pragma unroll
        for (int cc = 0; cc < 8; ++cc) {
            f32x4 v = *reinterpret_cast<const f32x4*>(xr + cc * 4);
            const int c = cb + cc * 4;
            X1s[(c + 0) * 128 + r0] = hpk2(v.x, v.x);
            X1s[(c + 1) * 128 + r0] = hpk2(v.y, v.y);
            X1s[(c + 2) * 128 + r0] = hpk2(v.z, v.z);
            X1s[(c + 3) * 128 + r0] = hpk2(v.w, v.w);
        }
    };
    auto refillX2 = [&](int t) {
        const unsigned gb = (unsigned)(kk0 + t);   // col base = g*64
        #pragma unroll
        for (int mt = 0; mt < 4; ++mt) {
            const float* p = x2 + aoff[mt] + gb + qo;
            f32x4 lo0 = *reinterpret_cast<const f32x4*>(p);
            f32x4 lo1 = *reinterpret_cast<const f32x4*>(p + 4);
            f32x4 hi0 = *reinterpret_cast<const f32x4*>(p + 32);
            f32x4 hi1 = *reinterpret_cast<const f32x4*>(p + 36);
            x2h[mt][0] = __floats2half2_rn(lo0.x, lo0.y);
            x2h[mt][1] = __floats2half2_rn(lo0.z, lo0.w);
            x2h[mt][2] = __floats2half2_rn(lo1.x, lo1.y);
            x2h[mt][3] = __floats2half2_rn(lo1.z, lo1.w);
            x2h[mt][4] = __floats2half2_rn(hi0.x, hi0.y);
            x2h[mt][5] = __floats2half2_rn(hi0.z, hi0.w);
            x2h[mt][6] = __floats2half2_rn(hi1.x, hi1.y);
            x2h[mt][7] = __floats2half2_rn(hi1.z, hi1.w);
        }
    };

#define GL_BODY(T, FU, FP)                                                        \
    {                                                                             \
        const int t_ = (T);                                                       \
        const bool hn1 = (t_ + 1 < KITERS);                                       \
        if (hn1) loadF(t_ + 1, FP);                                               \
        if (hn1 && (((t_ + 1) & 63) != 0)) loadXC(t_ + 1, xn);                    \
        _Pragma("unroll")                                                         \
        for (int ks = 0; ks < 2; ++ks) {                                          \
            f16x8 af[4];                                                          \
            _Pragma("unroll")                                                     \
            for (int mt = 0; mt < 4; ++mt) {                                      \
                u32x4 pk;                                                         \
                pk[0] = h2u(__hmul2(xc[mt], x2h[mt][ks * 4 + 0]));                \
                pk[1] = h2u(__hmul2(xc[mt], x2h[mt][ks * 4 + 1]));                \
                pk[2] = h2u(__hmul2(xc[mt], x2h[mt][ks * 4 + 2]));                \
                pk[3] = h2u(__hmul2(xc[mt], x2h[mt][ks * 4 + 3]));                \
                af[mt] = __builtin_bit_cast(f16x8, pk);                           \
            }                                                                     \
            _Pragma("unroll")                                                     \
            for (int mt = 0; mt < 4; ++mt)                                        \
                _Pragma("unroll")                                                 \
                for (int nt = 0; nt < 4; ++nt)                                    \
                    acc[mt][nt] = __builtin_amdgcn_mfma_f32_16x16x32_f16(         \
                        af[mt], FU[ks * 4 + nt], acc[mt][nt], 0, 0, 0);           \
        }                                                                         \
        _Pragma("unroll")                                                         \
        for (int mt = 0; mt < 4; ++mt) xc[mt] = xn[mt];                           \
    }

    loadF(0, fE);                           // prologue frag prefetch

    for (int itb = 0; itb < KITERS; itb += 2) {
        if ((itb & 63) == 0) {              // g boundary (always even)
            __syncthreads();                // all waves done reading old X1s slab
            stageX1(itb);
            refillX2(itb);
            __syncthreads();                // slab visible to all waves
            loadXC(itb, xc);
        }
        // even sub-iter: consume fE, prefetch F(itb+1) -> fO
        GL_BODY(itb,     fE, fO)
        // odd  sub-iter: consume fO, prefetch F(itb+2) -> fE
        GL_BODY(itb + 1, fO, fE)
    }
#undef GL_BODY

    // Epilogue: split-K partials. C/D: row(m)=quad*4+reg, col(n)=lane&15.
    #pragma unroll
    for (int mt = 0; mt < 4; ++mt) {
        const int mb = m0 + wm + mt * 16 + quad * 4;
        #pragma unroll
        for (int nt = 0; nt < 4; ++nt) {
            const int n = n0 + wn + nt * 16 + l16;
            #pragma unroll
            for (int r = 0; r < 4; ++r)
                unsafeAtomicAdd(&out[(mb + r) * O_DIM + n], acc[mt][nt][r]);
        }
    }
}

// ---- fallback (fp32 W, LDS staging) if workspace too small for Wt ----
constexpr int STR = 72;
__global__ __launch_bounds__(256, 2) void gl_gemm_fb(const float* __restrict__ x1,
                                                     const float* __restrict__ x2,
                                                     const float* __restrict__ W,
                                                     float* __restrict__ out) {
    __shared__ unsigned short Ab[BM * STR];
    __shared__ unsigned short Bb2[BM * STR];

    const int tid  = threadIdx.x;
    const int lane = tid & 63;
    const int wid  = tid >> 6;
    const int wm   = (wid >> 1) * 64;
    const int wn   = (wid & 1) * 64;
    const int quad = lane >> 4;
    const int l16  = lane & 15;
    const int m0   = blockIdx.y * BM;
    const int n0   = blockIdx.x * BN;
    const int kk0  = blockIdx.z * (1024 / 4);

    const int srow = tid >> 4;
    const int scol = (tid & 15) * 4;

    f32x4 acc[4][4] = {};

    for (int kk = kk0; kk < kk0 + (1024 / 4); ++kk) {
        const int g = kk >> 6;
        const int i = kk & 63;
        __syncthreads();
        #pragma unroll
        for (int c = 0; c < 8; ++c) {
            const int r = srow + c * 16;
            const float x1v = x1[(m0 + r) * H_DIM + g * 64 + i];
            const f32x4 v = *reinterpret_cast<const f32x4*>(
                &x2[(m0 + r) * H_DIM + g * 64 + scol]);
            ushort4 h;
            h.x = f2b(v.x * x1v); h.y = f2b(v.y * x1v);
            h.z = f2b(v.z * x1v); h.w = f2b(v.w * x1v);
            *reinterpret_cast<ushort4*>(&Ab[r * STR + scol]) = h;
        }
        #pragma unroll
        for (int c = 0; c < 8; ++c) {
            const int r = srow + c * 16;
            const f32x4 v = *reinterpret_cast<const f32x4*>(
                &W[(size_t)(n0 + r) * KDIM + (size_t)kk * 64 + scol]);
            ushort4 h;
            h.x = f2b(v.x); h.y = f2b(v.y); h.z = f2b(v.z); h.w = f2b(v.w);
            *reinterpret_cast<ushort4*>(&Bb2[r * STR + scol]) = h;
        }
        __syncthreads();
        #pragma unroll
        for (int ks = 0; ks < 2; ++ks) {
            const int koff = ks * 32 + quad * 8;
            bf16x8 af[4], bfr[4];
            #pragma unroll
            for (int mt = 0; mt < 4; ++mt)
                af[mt] = *reinterpret_cast<const bf16x8*>(
                    &Ab[(wm + mt * 16 + l16) * STR + koff]);
            #pragma unroll
            for (int nt = 0; nt < 4; ++nt)
                bfr[nt] = *reinterpret_cast<const bf16x8*>(
                    &Bb2[(wn + nt * 16 + l16) * STR + koff]);
            #pragma unroll
            for (int mt = 0; mt < 4; ++mt)
                #pragma unroll
                for (int nt = 0; nt < 4; ++nt)
                    acc[mt][nt] = __builtin_amdgcn_mfma_f32_16x16x32_bf16(
                        af[mt], bfr[nt], acc[mt][nt], 0, 0, 0);
        }
    }
    #pragma unroll
    for (int mt = 0; mt < 4; ++mt) {
        const int mb = m0 + wm + mt * 16 + quad * 4;
        #pragma unroll
        for (int nt = 0; nt < 4; ++nt) {
            const int n = n0 + wn + nt * 16 + l16;
            #pragma unroll
            for (int r = 0; r < 4; ++r)
                unsafeAtomicAdd(&out[(mb + r) * O_DIM + n], acc[mt][nt][r]);
        }
    }
}

extern "C" void kernel_launch(void* const* d_in, const int* in_sizes, int n_in,
                              void* d_out, int out_size, void* d_ws, size_t ws_size,
                              hipStream_t stream) {
    const float* x1 = (const float*)d_in[0];
    const float* x2 = (const float*)d_in[1];
    const float* W  = (const float*)d_in[2];
    const float* b  = (const float*)d_in[3];
    float* out = (float*)d_out;

    const size_t wt_bytes = (size_t)O_DIM * KDIM * sizeof(unsigned short); // 134 MB

    if (ws_size >= wt_bytes) {
        unsigned short* Wt = (unsigned short*)d_ws;
        // fused bias-init + fragment swizzle (grid MUST be 2048x256 for init coverage)
        w_cvt<<<dim3(2048), dim3(256), 0, stream>>>(W, Wt, b, out);
        // 1D grid: 8(n) x 16(m) x 8(k) = 1024 blocks; 3/CU resident (VGPR-bound),
        // 256 backfill as blocks retire.
        gl_gemm<<<dim3(8 * 16 * SPLITK), dim3(256), 0, stream>>>(x1, x2, Wt, out);
    } else {
        gl_init<<<dim3((L_DIM * O_DIM / 4) / 256), dim3(256), 0, stream>>>(b, out);
        dim3 grid(O_DIM / BN, L_DIM / BM, 4);
        gl_gemm_fb<<<grid, dim3(256), 0, stream>>>(x1, x2, W, out);
    }
}

// Round 8
// 629.722 us; speedup vs baseline: 1.8171x; 1.8171x over previous
//
#include <hip/hip_runtime.h>
#include <hip/hip_bf16.h>
#include <hip/hip_fp16.h>
#include <stdint.h>

// GroupLinear: out[l,o] = sum_{g,i,j} x1[l,g*64+i]*x2[l,g*64+j]*W[o,(g*64+i)*64+j] + b[o]
// Round 15: revert r14's occupancy push (launch_bounds(256,3) forced VGPR 164->84,
// 520MB scratch spills, 3x regression). GEMM = exact r13 (252us, MfmaUtil 53%).
// New: w_cvt rewritten as LDS transpose. Old version's read was a 16-row 256KB-stride
// scatter (~175us for 402MB). New: coalesced f32 reads (16 thr/row, 256B runs),
// fp32->fp16 convert on load, XOR-swizzled 16KB LDS tile (u32idx ^= (row&7)<<2,
// 8 lanes/bank-group = b128 optimum both phases), 1KB contiguous unit writes.

#define L_DIM 2048
#define H_DIM 1024
#define O_DIM 1024
#define KDIM  65536

constexpr int BM = 128, BN = 128;
constexpr int SPLITK = 4;
constexpr int KITERS = 1024 / SPLITK;   // 256 (g,i) pairs per block, K-advance 64 each

typedef __attribute__((ext_vector_type(8))) _Float16 f16x8;
typedef __attribute__((ext_vector_type(8))) short bf16x8;
typedef __attribute__((ext_vector_type(8))) unsigned short u16x8;
typedef __attribute__((ext_vector_type(4))) float f32x4;
typedef __attribute__((ext_vector_type(4))) unsigned int u32x4;

__device__ __forceinline__ unsigned short f2b(float x) {
    __hip_bfloat16 h = __float2bfloat16(x);
    unsigned short u;
    __builtin_memcpy(&u, &h, 2);
    return u;
}

__device__ __forceinline__ unsigned hpk2(float a, float b) {   // two f32 -> packed half2
    __half2 h = __floats2half2_rn(a, b);
    unsigned u;
    __builtin_memcpy(&u, &h, 4);
    return u;
}

__device__ __forceinline__ unsigned h2u(__half2 h) {           // half2 bits -> unsigned
    unsigned u;
    __builtin_memcpy(&u, &h, 4);
    return u;
}

// ---- fused: bias-init AND W fp32 -> Wt fp16 fragment-order swizzle (LDS transpose) --
// Grid must be exactly 2048 x 256 (init covers 2M floats; 8192 tiles = 2048 x 4).
// Wt[((kc*64 + nt)*64 + lane)*8 + e] = fp16(W[nt*16 + (lane&15)][kc*32 + (lane>>4)*8 + e])
__global__ __launch_bounds__(256) void w_cvt(const float* __restrict__ W,
                                             unsigned short* __restrict__ Wt,
                                             const float* __restrict__ bias,
                                             float* __restrict__ out) {
    __shared__ unsigned lds[4096];          // 16 KB: one 16x512 fp16 tile (u32 units)

    const int t = threadIdx.x;
    {   // bias init (atomic-accumulation base)
        const int idx = blockIdx.x * 256 + t;
        const int o = (idx * 4) & (O_DIM - 1);
        f32x4 bv = *reinterpret_cast<const f32x4*>(bias + o);
        reinterpret_cast<f32x4*>(out)[idx] = bv;
    }

    const int lane = t & 63;
    const int quad = lane >> 4;
    const int l16  = lane & 15;
    const int wv   = t >> 6;

    // phase-A role: row = t>>4 (0..15), col chunk base = (t&15)*8 floats
    const int ar = t >> 4;
    const int ac = (t & 15) * 8;

    for (int i = 0; i < 4; ++i) {
        const int tt  = blockIdx.x * 4 + i;     // tile index
        const int nt  = tt & 63;                // 16-row group
        const int kcb = tt >> 6;                // 512-col group (16 kc units)

        if (i) __syncthreads();                 // LDS reuse guard

        // phase A: coalesced read 16x512 fp32, convert, swizzled LDS store
        const float* src = W + (size_t)(nt * 16 + ar) * KDIM + (size_t)kcb * 512 + ac;
        #pragma unroll
        for (int i2 = 0; i2 < 4; ++i2) {
            f32x4 a = *reinterpret_cast<const f32x4*>(src + i2 * 128);
            f32x4 b = *reinterpret_cast<const f32x4*>(src + i2 * 128 + 4);
            u32x4 pk;
            pk[0] = hpk2(a.x, a.y); pk[1] = hpk2(a.z, a.w);
            pk[2] = hpk2(b.x, b.y); pk[3] = hpk2(b.z, b.w);
            const int u32i = (ar * 256 + (ac >> 1) + i2 * 64) ^ ((ar & 7) << 2);
            *reinterpret_cast<u32x4*>(&lds[u32i]) = pk;
        }
        __syncthreads();

        // phase B: swizzled LDS read -> contiguous 1KB fragment-unit writes
        #pragma unroll
        for (int jj = 0; jj < 4; ++jj) {
            const int j = wv * 4 + jj;          // kc within tile (0..15)
            const int u32i = ((l16) * 256 + j * 16 + quad * 4) ^ ((l16 & 7) << 2);
            u32x4 v = *reinterpret_cast<const u32x4*>(&lds[u32i]);
            const size_t u = (size_t)(kcb * 16 + j) * 64 + nt;
            *reinterpret_cast<u32x4*>(Wt + u * 512 + lane * 8) = v;
        }
    }
}

// ---- standalone init (fallback path only) ----
__global__ __launch_bounds__(256) void gl_init(const float* __restrict__ bias,
                                               float* __restrict__ out) {
    int idx = blockIdx.x * 256 + threadIdx.x;
    int o = (idx * 4) & (O_DIM - 1);
    f32x4 bv = *reinterpret_cast<const f32x4*>(bias + o);
    reinterpret_cast<f32x4*>(out)[idx] = bv;
}

// ---- main GEMM: fp16 frags direct from Wt; pk_mul A-build; no W LDS/barriers ----
// EXACT r13 structure (252us measured): 2 blocks/CU, VGPR 100+64acc.
__global__ __launch_bounds__(256, 2) void gl_gemm(const float* __restrict__ x1,
                                                  const float* __restrict__ x2,
                                                  const unsigned short* __restrict__ Wt,
                                                  float* __restrict__ out) {
    __shared__ unsigned X1s[64 * 128];            // 32 KB, [col][row], dup'd half2

    const int tid  = threadIdx.x;
    const int lane = tid & 63;
    const int wid  = tid >> 6;
    const int wm   = (wid >> 1) * 64;
    const int wn   = (wid & 1) * 64;
    const int quad = lane >> 4;
    const int l16  = lane & 15;

    // n in low 3 bits -> blocks sharing one W n-slab co-locate per XCD (L2 reuse)
    const int id  = blockIdx.x;
    const int n0  = (id & 7) * BN;
    const int m0  = ((id >> 3) & 15) * BM;
    const int kk0 = (id >> 7) * KITERS;     // (g,i)-pair index base, multiple of 64

    unsigned aoff[4];                       // x1/x2 row offsets (floats)
    #pragma unroll
    for (int tt = 0; tt < 4; ++tt)
        aoff[tt] = (unsigned)(m0 + wm + tt * 16 + l16) * H_DIM;
    const unsigned qo = quad * 8;

    // per-thread B-frag base: Wt element ((kc*64 + ntile)*64 + lane)*8
    const unsigned short* gWt = Wt + (size_t)kk0 * 65536
                                   + (size_t)((n0 + wn) >> 4) * 512 + lane * 8;

    f32x4 acc[4][4] = {};
    __half2 x2h[4][8];      // per-g x2 slice: [mt][ks*4 + pair], pairs of j at ks*32+qo
    f16x8 fE[8], fO[8];     // NAMED frag sets, depth-1 prefetch (rule #20)
    __half2 xc[4], xn[4];   // x1 current / next (duplicated halves)

    auto loadF = [&](int t, f16x8 (&f)[8]) {
        const unsigned short* p = gWt + (size_t)t * 65536;
        #pragma unroll
        for (int ks = 0; ks < 2; ++ks)
            #pragma unroll
            for (int nt = 0; nt < 4; ++nt)
                f[ks * 4 + nt] = *reinterpret_cast<const f16x8*>(
                    p + ks * 32768 + nt * 512);
    };
    auto loadXC = [&](int t, __half2 (&v)[4]) {
        const unsigned* xp = &X1s[(t & 63) * 128 + wm + l16];
        unsigned a = xp[0], b = xp[16], c = xp[32], d = xp[48];
        __builtin_memcpy(&v[0], &a, 4); __builtin_memcpy(&v[1], &b, 4);
        __builtin_memcpy(&v[2], &c, 4); __builtin_memcpy(&v[3], &d, 4);
    };
    auto stageX1 = [&](int t) {             // stage x1 g-slab -> X1s[col][row] dup'd half2
        const int r0 = tid >> 1;
        const int cb = (tid & 1) * 32;
        const float* xr = x1 + (size_t)(m0 + r0) * H_DIM + (unsigned)(kk0 + t) + cb;
        #pragma unroll
        for (int cc = 0; cc < 8; ++cc) {
            f32x4 v = *reinterpret_cast<const f32x4*>(xr + cc * 4);
            const int c = cb + cc * 4;
            X1s[(c + 0) * 128 + r0] = hpk2(v.x, v.x);
            X1s[(c + 1) * 128 + r0] = hpk2(v.y, v.y);
            X1s[(c + 2) * 128 + r0] = hpk2(v.z, v.z);
            X1s[(c + 3) * 128 + r0] = hpk2(v.w, v.w);
        }
    };
    auto refillX2 = [&](int t) {
        const unsigned gb = (unsigned)(kk0 + t);   // col base = g*64
        #pragma unroll
        for (int mt = 0; mt < 4; ++mt) {
            const float* p = x2 + aoff[mt] + gb + qo;
            f32x4 lo0 = *reinterpret_cast<const f32x4*>(p);
            f32x4 lo1 = *reinterpret_cast<const f32x4*>(p + 4);
            f32x4 hi0 = *reinterpret_cast<const f32x4*>(p + 32);
            f32x4 hi1 = *reinterpret_cast<const f32x4*>(p + 36);
            x2h[mt][0] = __floats2half2_rn(lo0.x, lo0.y);
            x2h[mt][1] = __floats2half2_rn(lo0.z, lo0.w);
            x2h[mt][2] = __floats2half2_rn(lo1.x, lo1.y);
            x2h[mt][3] = __floats2half2_rn(lo1.z, lo1.w);
            x2h[mt][4] = __floats2half2_rn(hi0.x, hi0.y);
            x2h[mt][5] = __floats2half2_rn(hi0.z, hi0.w);
            x2h[mt][6] = __floats2half2_rn(hi1.x, hi1.y);
            x2h[mt][7] = __floats2half2_rn(hi1.z, hi1.w);
        }
    };

#define GL_BODY(T, FU, FP)                                                        \
    {                                                                             \
        const int t_ = (T);                                                       \
        const bool hn1 = (t_ + 1 < KITERS);                                       \
        if (hn1) loadF(t_ + 1, FP);                                               \
        if (hn1 && (((t_ + 1) & 63) != 0)) loadXC(t_ + 1, xn);                    \
        _Pragma("unroll")                                                         \
        for (int ks = 0; ks < 2; ++ks) {                                          \
            f16x8 af[4];                                                          \
            _Pragma("unroll")                                                     \
            for (int mt = 0; mt < 4; ++mt) {                                      \
                u32x4 pk;                                                         \
                pk[0] = h2u(__hmul2(xc[mt], x2h[mt][ks * 4 + 0]));                \
                pk[1] = h2u(__hmul2(xc[mt], x2h[mt][ks * 4 + 1]));                \
                pk[2] = h2u(__hmul2(xc[mt], x2h[mt][ks * 4 + 2]));                \
                pk[3] = h2u(__hmul2(xc[mt], x2h[mt][ks * 4 + 3]));                \
                af[mt] = __builtin_bit_cast(f16x8, pk);                           \
            }                                                                     \
            _Pragma("unroll")                                                     \
            for (int mt = 0; mt < 4; ++mt)                                        \
                _Pragma("unroll")                                                 \
                for (int nt = 0; nt < 4; ++nt)                                    \
                    acc[mt][nt] = __builtin_amdgcn_mfma_f32_16x16x32_f16(         \
                        af[mt], FU[ks * 4 + nt], acc[mt][nt], 0, 0, 0);           \
        }                                                                         \
        _Pragma("unroll")                                                         \
        for (int mt = 0; mt < 4; ++mt) xc[mt] = xn[mt];                           \
    }

    loadF(0, fE);                           // prologue frag prefetch

    for (int itb = 0; itb < KITERS; itb += 2) {
        if ((itb & 63) == 0) {              // g boundary (always even)
            __syncthreads();                // all waves done reading old X1s slab
            stageX1(itb);
            refillX2(itb);
            __syncthreads();                // slab visible to all waves
            loadXC(itb, xc);
        }
        // even sub-iter: consume fE, prefetch F(itb+1) -> fO
        GL_BODY(itb,     fE, fO)
        // odd  sub-iter: consume fO, prefetch F(itb+2) -> fE
        GL_BODY(itb + 1, fO, fE)
    }
#undef GL_BODY

    // Epilogue: split-K partials. C/D: row(m)=quad*4+reg, col(n)=lane&15.
    #pragma unroll
    for (int mt = 0; mt < 4; ++mt) {
        const int mb = m0 + wm + mt * 16 + quad * 4;
        #pragma unroll
        for (int nt = 0; nt < 4; ++nt) {
            const int n = n0 + wn + nt * 16 + l16;
            #pragma unroll
            for (int r = 0; r < 4; ++r)
                unsafeAtomicAdd(&out[(mb + r) * O_DIM + n], acc[mt][nt][r]);
        }
    }
}

// ---- fallback (fp32 W, LDS staging) if workspace too small for Wt ----
constexpr int STR = 72;
__global__ __launch_bounds__(256, 2) void gl_gemm_fb(const float* __restrict__ x1,
                                                     const float* __restrict__ x2,
                                                     const float* __restrict__ W,
                                                     float* __restrict__ out) {
    __shared__ unsigned short Ab[BM * STR];
    __shared__ unsigned short Bb2[BM * STR];

    const int tid  = threadIdx.x;
    const int lane = tid & 63;
    const int wid  = tid >> 6;
    const int wm   = (wid >> 1) * 64;
    const int wn   = (wid & 1) * 64;
    const int quad = lane >> 4;
    const int l16  = lane & 15;
    const int m0   = blockIdx.y * BM;
    const int n0   = blockIdx.x * BN;
    const int kk0  = blockIdx.z * (1024 / 4);

    const int srow = tid >> 4;
    const int scol = (tid & 15) * 4;

    f32x4 acc[4][4] = {};

    for (int kk = kk0; kk < kk0 + (1024 / 4); ++kk) {
        const int g = kk >> 6;
        const int i = kk & 63;
        __syncthreads();
        #pragma unroll
        for (int c = 0; c < 8; ++c) {
            const int r = srow + c * 16;
            const float x1v = x1[(m0 + r) * H_DIM + g * 64 + i];
            const f32x4 v = *reinterpret_cast<const f32x4*>(
                &x2[(m0 + r) * H_DIM + g * 64 + scol]);
            ushort4 h;
            h.x = f2b(v.x * x1v); h.y = f2b(v.y * x1v);
            h.z = f2b(v.z * x1v); h.w = f2b(v.w * x1v);
            *reinterpret_cast<ushort4*>(&Ab[r * STR + scol]) = h;
        }
        #pragma unroll
        for (int c = 0; c < 8; ++c) {
            const int r = srow + c * 16;
            const f32x4 v = *reinterpret_cast<const f32x4*>(
                &W[(size_t)(n0 + r) * KDIM + (size_t)kk * 64 + scol]);
            ushort4 h;
            h.x = f2b(v.x); h.y = f2b(v.y); h.z = f2b(v.z); h.w = f2b(v.w);
            *reinterpret_cast<ushort4*>(&Bb2[r * STR + scol]) = h;
        }
        __syncthreads();
        #pragma unroll
        for (int ks = 0; ks < 2; ++ks) {
            const int koff = ks * 32 + quad * 8;
            bf16x8 af[4], bfr[4];
            #pragma unroll
            for (int mt = 0; mt < 4; ++mt)
                af[mt] = *reinterpret_cast<const bf16x8*>(
                    &Ab[(wm + mt * 16 + l16) * STR + koff]);
            #pragma unroll
            for (int nt = 0; nt < 4; ++nt)
                bfr[nt] = *reinterpret_cast<const bf16x8*>(
                    &Bb2[(wn + nt * 16 + l16) * STR + koff]);
            #pragma unroll
            for (int mt = 0; mt < 4; ++mt)
                #pragma unroll
                for (int nt = 0; nt < 4; ++nt)
                    acc[mt][nt] = __builtin_amdgcn_mfma_f32_16x16x32_bf16(
                        af[mt], bfr[nt], acc[mt][nt], 0, 0, 0);
        }
    }
    #pragma unroll
    for (int mt = 0; mt < 4; ++mt) {
        const int mb = m0 + wm + mt * 16 + quad * 4;
        #pragma unroll
        for (int nt = 0; nt < 4; ++nt) {
            const int n = n0 + wn + nt * 16 + l16;
            #pragma unroll
            for (int r = 0; r < 4; ++r)
                unsafeAtomicAdd(&out[(mb + r) * O_DIM + n], acc[mt][nt][r]);
        }
    }
}

extern "C" void kernel_launch(void* const* d_in, const int* in_sizes, int n_in,
                              void* d_out, int out_size, void* d_ws, size_t ws_size,
                              hipStream_t stream) {
    const float* x1 = (const float*)d_in[0];
    const float* x2 = (const float*)d_in[1];
    const float* W  = (const float*)d_in[2];
    const float* b  = (const float*)d_in[3];
    float* out = (float*)d_out;

    const size_t wt_bytes = (size_t)O_DIM * KDIM * sizeof(unsigned short); // 134 MB

    if (ws_size >= wt_bytes) {
        unsigned short* Wt = (unsigned short*)d_ws;
        // fused bias-init + LDS-transpose swizzle (grid MUST be 2048x256)
        w_cvt<<<dim3(2048), dim3(256), 0, stream>>>(W, Wt, b, out);
        // 1D grid: 8(n) x 16(m) x 4(k) = 512 blocks = exact 2/CU at bounds(256,2)
        gl_gemm<<<dim3(8 * 16 * SPLITK), dim3(256), 0, stream>>>(x1, x2, Wt, out);
    } else {
        gl_init<<<dim3((L_DIM * O_DIM / 4) / 256), dim3(256), 0, stream>>>(b, out);
        dim3 grid(O_DIM / BN, L_DIM / BM, 4);
        gl_gemm_fb<<<grid, dim3(256), 0, stream>>>(x1, x2, W, out);
    }
}